// Round 6
// baseline (968.200 us; speedup 1.0000x reference)
//
#include <hip/hip_runtime.h>
#include <math.h>

#define BATCH 128
#define TLEN 512
#define XF 266
#define HID 192
#define NC 250

typedef __attribute__((ext_vector_type(8))) short short8;
typedef __attribute__((ext_vector_type(4))) float float4v;

// fp32 -> bf16 (RNE)
__device__ __forceinline__ unsigned short f2bf(float f) {
  unsigned u = __float_as_uint(f);
  u += 0x7FFF + ((u >> 16) & 1);
  return (unsigned short)(u >> 16);
}

__device__ __forceinline__ float fast_sigmoid(float x) {
  float t = __expf(-x);
  return __builtin_amdgcn_rcpf(1.f + t);
}
// tanh(x) = 2*sigmoid(2x)-1
__device__ __forceinline__ float fast_tanh(float x) {
  float t = __expf(-2.f * x);
  return fmaf(2.f, __builtin_amdgcn_rcpf(1.f + t), -1.f);
}

// LDS-only barrier: does NOT drain vmcnt (global stores keep flying).
__device__ __forceinline__ void lds_barrier() {
  asm volatile("s_waitcnt lgkmcnt(0)\n\ts_barrier" ::: "memory");
}

// ---------------- K1: feature prep -> per-LSTM padded bf16 layouts --------
// featH*: [tile4][t512][m32][48]  (42 real + 6 zero)
// featA*: [tile2][t512][m64][8]   (6 real + 2 zero)

__device__ __forceinline__ void norm_hand(const float* __restrict__ xp,
                                          unsigned short* __restrict__ fp,
                                          int p0, int refp) {
  float rx = xp[2 * refp], ry = xp[2 * refp + 1];
  float px[21], py[21];
  float minx = 1e30f, maxx = -1e30f, miny = 1e30f, maxy = -1e30f;
#pragma unroll
  for (int i = 0; i < 21; ++i) {
    float ax = xp[2 * (p0 + i)] - rx;
    float ay = xp[2 * (p0 + i) + 1] - ry;
    px[i] = ax; py[i] = ay;
    minx = fminf(minx, ax); maxx = fmaxf(maxx, ax);
    miny = fminf(miny, ay); maxy = fmaxf(maxy, ay);
  }
  float s = fmaxf(maxx - minx, maxy - miny);
  if (s == 0.f) s = 1.f;
  float inv = 1.f / s;
#pragma unroll
  for (int i = 0; i < 21; ++i) {
    fp[2 * i] = f2bf(px[i] * inv);
    fp[2 * i + 1] = f2bf(py[i] * inv);
  }
  fp[42] = 0; fp[43] = 0; fp[44] = 0; fp[45] = 0; fp[46] = 0; fp[47] = 0;
}

__device__ __forceinline__ void norm_arm(const float* __restrict__ xp,
                                         unsigned short* __restrict__ fp,
                                         int a, int b, int c) {
  float rx = xp[0], ry = xp[1];
  float x0 = xp[2 * a] - rx, y0 = xp[2 * a + 1] - ry;
  float x1 = xp[2 * b] - rx, y1 = xp[2 * b + 1] - ry;
  float x2 = xp[2 * c] - rx, y2 = xp[2 * c + 1] - ry;
  float w = fmaxf(fmaxf(x0, x1), x2) - fminf(fminf(x0, x1), x2);
  float h = fmaxf(fmaxf(y0, y1), y2) - fminf(fminf(y0, y1), y2);
  float s = fmaxf(w, h);
  if (s == 0.f) s = 1.f;
  float inv = 1.f / s;
  fp[0] = f2bf(x0 * inv); fp[1] = f2bf(y0 * inv);
  fp[2] = f2bf(x1 * inv); fp[3] = f2bf(y1 * inv);
  fp[4] = f2bf(x2 * inv); fp[5] = f2bf(y2 * inv);
  fp[6] = 0; fp[7] = 0;
}

__global__ __launch_bounds__(256) void prep_kernel(
    const float* __restrict__ x,
    unsigned short* __restrict__ fHR, unsigned short* __restrict__ fHL,
    unsigned short* __restrict__ fAR, unsigned short* __restrict__ fAL) {
  int idx = blockIdx.x * 256 + threadIdx.x;
  if (idx >= BATCH * TLEN) return;
  int b = idx >> 9, t = idx & 511;
  const float* xp = x + (size_t)idx * XF;
  size_t hoff = (((size_t)(b >> 5) * TLEN + t) * 32 + (b & 31)) * 48;
  size_t aoff = (((size_t)(b >> 6) * TLEN + t) * 64 + (b & 63)) * 8;
  norm_hand(xp, fHR + hoff, 112, 10);  // right hand, ref pt 10
  norm_hand(xp, fHL + hoff, 91, 9);    // left hand, ref pt 9
  norm_arm (xp, fAR + aoff, 6, 8, 10); // right arm
  norm_arm (xp, fAL + aoff, 5, 7, 9);  // left arm
}

// ---------------- K1b: weight packing -> bf16 B^T [G][K] ------------------
// Hands K=128 = [wih(42)|0(22)|whh(64)]; Arms K=64 = [wih(6)|0(26)|whh(32)]

__global__ __launch_bounds__(256) void pack_kernel(
    const float* __restrict__ wi_rh, const float* __restrict__ wh_rh,
    const float* __restrict__ wi_ra, const float* __restrict__ wh_ra,
    const float* __restrict__ wi_lh, const float* __restrict__ wh_lh,
    const float* __restrict__ wi_la, const float* __restrict__ wh_la,
    unsigned short* __restrict__ bt_rh, unsigned short* __restrict__ bt_ra,
    unsigned short* __restrict__ bt_lh, unsigned short* __restrict__ bt_la) {
  int blk = blockIdx.x, tid = threadIdx.x;
  if (blk == 0) {
    for (int i = tid; i < 256 * 128; i += 256) {
      int g = i >> 7, k = i & 127;
      float v = (k < 42) ? wi_rh[g * 42 + k] : (k < 64 ? 0.f : wh_rh[g * 64 + (k - 64)]);
      bt_rh[i] = f2bf(v);
    }
  } else if (blk == 1) {
    for (int i = tid; i < 256 * 128; i += 256) {
      int g = i >> 7, k = i & 127;
      float v = (k < 42) ? wi_lh[g * 42 + k] : (k < 64 ? 0.f : wh_lh[g * 64 + (k - 64)]);
      bt_lh[i] = f2bf(v);
    }
  } else if (blk == 2) {
    for (int i = tid; i < 128 * 64; i += 256) {
      int g = i >> 6, k = i & 63;
      float v = (k < 6) ? wi_ra[g * 6 + k] : (k < 32 ? 0.f : wh_ra[g * 32 + (k - 32)]);
      bt_ra[i] = f2bf(v);
    }
  } else {
    for (int i = tid; i < 128 * 64; i += 256) {
      int g = i >> 6, k = i & 63;
      float v = (k < 6) ? wi_la[g * 6 + k] : (k < 32 ? 0.f : wh_la[g * 32 + (k - 32)]);
      bt_la[i] = f2bf(v);
    }
  }
}

// ---------------- K2: MFMA LSTM recurrence --------------------------------
// 512-thread blocks, 8 waves = 2 waves/SIMD for latency hiding.
// Hands (MB=32): waves = (batch-group bg 0..1) x (j-group jg 0..3).
// Arms  (MB=64): waves = (bg 0..3) x (jg 0..1).
// A row (hands, STR=142 pad): [x 0..47 | 0 48..63 | h 64..127 | pad]
// A row (arms,  STR=78  pad): [x 0..7  | 0 8..31  | h 32..63  | pad]
// STR chosen so lane stride in banks is odd -> conflict-free b128 reads.
// Double-buffered, ONE lds-only barrier/step (no vmcnt drain).

template <int H, int CH, int STR, int MB, int SCH>
__device__ __forceinline__ void lstm_core(
    unsigned short* __restrict__ Ab0, unsigned short* __restrict__ Ab1,
    const unsigned short* __restrict__ Bt,
    const float* __restrict__ bi, const float* __restrict__ bh,
    const unsigned short* __restrict__ featp,
    float* __restrict__ comb,   // combined + coff
    int b0, int mrow0, int j0) {
  constexpr int K = CH * 32;
  constexpr int HOFF = K - H;
  constexpr int XSH = MB * SCH * 8;  // shorts per t-slice
  int tid = threadIdx.x;
  int lane = tid & 63, n = lane & 15, quad = lane >> 4;

  // B fragments + bias (registers, loaded once)
  short8 Vb[4][CH];
  float bias[4];
#pragma unroll
  for (int q = 0; q < 4; ++q) {
    int g = q * H + j0 + n;
    bias[q] = bi[g] + bh[g];
#pragma unroll
    for (int c = 0; c < CH; ++c)
      Vb[q][c] = *(const short8*)(Bt + (size_t)g * K + c * 32 + quad * 8);
  }

  // zero both buffers (pads + initial h=0), stage x_0 into buf0
  for (int i = tid; i < MB * STR; i += 512) { Ab0[i] = 0; Ab1[i] = 0; }
  bool st = tid < MB * SCH;
  int sm = tid / SCH, sc8 = tid % SCH;
  unsigned short* xd0 = Ab0 + sm * STR + sc8 * 8;
  unsigned short* xd1 = Ab1 + sm * STR + sc8 * 8;
  const unsigned short* fp = featp + tid * 8;
  if (st) *(short8*)xd0 = *(const short8*)fp;
  fp += XSH;  // -> t=1 slice
  float4v cc = {0.f, 0.f, 0.f, 0.f};
  __syncthreads();

  const unsigned short* ard0 = Ab0 + (mrow0 + n) * STR;
  const unsigned short* ard1 = Ab1 + (mrow0 + n) * STR;
  unsigned short* hw0 = Ab0 + (mrow0 + quad * 4) * STR + HOFF + j0 + n;
  unsigned short* hw1 = Ab1 + (mrow0 + quad * 4) * STR + HOFF + j0 + n;

  float* cp0 = comb + ((size_t)(b0 + mrow0 + quad * 4 + 0) * TLEN) * HID + j0 + n;
  float* cp1 = comb + ((size_t)(b0 + mrow0 + quad * 4 + 1) * TLEN) * HID + j0 + n;
  float* cp2 = comb + ((size_t)(b0 + mrow0 + quad * 4 + 2) * TLEN) * HID + j0 + n;
  float* cp3 = comb + ((size_t)(b0 + mrow0 + quad * 4 + 3) * TLEN) * HID + j0 + n;

  for (int t = 0; t < TLEN; ++t) {
    int par = t & 1;
    short8 xv;
    bool doPf = st && (t + 1 < TLEN);
    if (doPf) xv = *(const short8*)fp;
    fp += XSH;

    const unsigned short* ard = par ? ard1 : ard0;
    short8 Va[CH];
#pragma unroll
    for (int c = 0; c < CH; ++c)
      Va[c] = *(const short8*)(ard + c * 32 + quad * 8);

    float4v acc[4];
#pragma unroll
    for (int q = 0; q < 4; ++q) {
      acc[q] = (float4v){bias[q], bias[q], bias[q], bias[q]};
#pragma unroll
      for (int c = 0; c < CH; ++c)
        acc[q] = __builtin_amdgcn_mfma_f32_16x16x32_bf16(Va[c], Vb[q][c], acc[q], 0, 0, 0);
    }

    unsigned short* hw = par ? hw0 : hw1;  // write the buffer we'll read next
#pragma unroll
    for (int r = 0; r < 4; ++r) {
      float gi = fast_sigmoid(acc[0][r]);
      float gf = fast_sigmoid(acc[1][r]);
      float gg = fast_tanh(acc[2][r]);
      float go = fast_sigmoid(acc[3][r]);
      float cv = fmaf(gf, cc[r], gi * gg);
      cc[r] = cv;
      float h = go * fast_tanh(cv);
      hw[r * STR] = f2bf(h);
      if (r == 0) { *cp0 = h; cp0 += HID; }
      else if (r == 1) { *cp1 = h; cp1 += HID; }
      else if (r == 2) { *cp2 = h; cp2 += HID; }
      else { *cp3 = h; cp3 += HID; }
    }

    if (doPf) *(short8*)(par ? xd0 : xd1) = xv;
    lds_barrier();
  }
}

__global__ __launch_bounds__(512, 2) void lstm_kernel(
    const unsigned short* __restrict__ fHR, const unsigned short* __restrict__ fHL,
    const unsigned short* __restrict__ fAR, const unsigned short* __restrict__ fAL,
    const unsigned short* __restrict__ bt_rh, const unsigned short* __restrict__ bt_ra,
    const unsigned short* __restrict__ bt_lh, const unsigned short* __restrict__ bt_la,
    const float* __restrict__ b0i, const float* __restrict__ b0h,
    const float* __restrict__ b1i, const float* __restrict__ b1h,
    const float* __restrict__ b2i, const float* __restrict__ b2h,
    const float* __restrict__ b3i, const float* __restrict__ b3h,
    float* __restrict__ combined) {
  __shared__ __align__(16) unsigned short A0[4992];  // max(32*142, 64*78)
  __shared__ __align__(16) unsigned short A1[4992];
  int blk = blockIdx.x;
  int wave = threadIdx.x >> 6;
  if (blk < 8) {          // hands: H=64, MB=32; blk 0..3 RH, 4..7 LH
    int tl = blk & 3;
    bool left = blk >= 4;
    lstm_core<64, 4, 142, 32, 6>(
        A0, A1, left ? bt_lh : bt_rh, left ? b2i : b0i, left ? b2h : b0h,
        (left ? fHL : fHR) + (size_t)tl * TLEN * 1536,
        combined + (left ? 96 : 0), tl * 32, (wave >> 2) * 16, (wave & 3) * 16);
  } else {                // arms: H=32, MB=64; blk 8..9 RA, 10..11 LA
    int a = blk - 8;
    int tl = a & 1;
    bool left = a >= 2;
    lstm_core<32, 2, 78, 64, 1>(
        A0, A1, left ? bt_la : bt_ra, left ? b3i : b1i, left ? b3h : b1h,
        (left ? fAL : fAR) + (size_t)tl * TLEN * 512,
        combined + (left ? 160 : 64), tl * 64, (wave >> 1) * 16, (wave & 1) * 16);
  }
}

// ---------------- K3: attention + FC (512 threads, latency-hidden) --------

__global__ __launch_bounds__(512) void attn_kernel(const float* __restrict__ combined,
                                                   const float* __restrict__ att_w,
                                                   const float* __restrict__ fc_w,
                                                   const float* __restrict__ fc_b,
                                                   float* __restrict__ dout) {
  __shared__ float sc[TLEN];
  __shared__ float aw[HID];
  __shared__ float pctx[8][HID];
  __shared__ float ctx[HID];
  __shared__ float red[8];
  int b = blockIdx.x, tid = threadIdx.x;
  int lane = tid & 63, wave = tid >> 6;
  const float* cb = combined + (size_t)b * TLEN * HID;
  if (tid < HID) aw[tid] = att_w[tid];
  __syncthreads();
  float a0 = aw[lane], a1 = aw[lane + 64], a2 = aw[lane + 128];

  // scores: each wave 64 t's, 2 in flight
  int t0 = wave * 64;
  for (int t = t0; t < t0 + 64; t += 2) {
    const float* r0 = cb + (size_t)t * HID;
    const float* r1 = r0 + HID;
    float p0 = a0 * r0[lane] + a1 * r0[lane + 64] + a2 * r0[lane + 128];
    float p1 = a0 * r1[lane] + a1 * r1[lane + 64] + a2 * r1[lane + 128];
#pragma unroll
    for (int o = 32; o; o >>= 1) {
      p0 += __shfl_xor(p0, o, 64);
      p1 += __shfl_xor(p1, o, 64);
    }
    if (lane == 0) { sc[t] = p0; sc[t + 1] = p1; }
  }
  __syncthreads();

  // softmax: one t per thread
  float e = sc[tid];
  float lmax = e;
#pragma unroll
  for (int o = 32; o; o >>= 1) lmax = fmaxf(lmax, __shfl_xor(lmax, o, 64));
  if (lane == 0) red[wave] = lmax;
  __syncthreads();
  float m = red[0];
#pragma unroll
  for (int w = 1; w < 8; ++w) m = fmaxf(m, red[w]);
  __syncthreads();
  float ex = __expf(e - m);
  float ls = ex;
#pragma unroll
  for (int o = 32; o; o >>= 1) ls += __shfl_xor(ls, o, 64);
  if (lane == 0) red[wave] = ls;
  __syncthreads();
  float S = red[0];
#pragma unroll
  for (int w = 1; w < 8; ++w) S += red[w];
  float wgt = ex / S;
  sc[tid] = wgt;
  dout[BATCH * NC + b * TLEN + tid] = wgt;  // weights output (B,T,1)
  __syncthreads();

  // context: coalesced (lanes = h), 8 t-groups reduced via LDS
#pragma unroll
  for (int p = 0; p < 3; ++p) {
    int h = p * 64 + lane;
    float c0 = 0.f, c1 = 0.f, c2 = 0.f, c3 = 0.f;
    for (int t = t0; t < t0 + 64; t += 4) {
      c0 += sc[t] * cb[(size_t)t * HID + h];
      c1 += sc[t + 1] * cb[(size_t)(t + 1) * HID + h];
      c2 += sc[t + 2] * cb[(size_t)(t + 2) * HID + h];
      c3 += sc[t + 3] * cb[(size_t)(t + 3) * HID + h];
    }
    pctx[wave][h] = (c0 + c1) + (c2 + c3);
  }
  __syncthreads();
  if (tid < HID) {
    float s = pctx[0][tid];
#pragma unroll
    for (int w = 1; w < 8; ++w) s += pctx[w][tid];
    ctx[tid] = s;
  }
  __syncthreads();

  // FC
  if (tid < NC) {
    const float* wr = fc_w + (size_t)tid * HID;
    float s0 = fc_b[tid], s1 = 0.f, s2 = 0.f, s3 = 0.f;
#pragma unroll
    for (int h = 0; h < HID; h += 4) {
      s0 += ctx[h] * wr[h];
      s1 += ctx[h + 1] * wr[h + 1];
      s2 += ctx[h + 2] * wr[h + 2];
      s3 += ctx[h + 3] * wr[h + 3];
    }
    dout[b * NC + tid] = (s0 + s1) + (s2 + s3);  // logits (B,250)
  }
}

// ---------------- launcher ----------------

extern "C" void kernel_launch(void* const* d_in, const int* in_sizes, int n_in,
                              void* d_out, int out_size, void* d_ws, size_t ws_size,
                              hipStream_t stream) {
  const float* x = (const float*)d_in[0];
  const float* wih_rh = (const float*)d_in[1];
  const float* whh_rh = (const float*)d_in[2];
  const float* bih_rh = (const float*)d_in[3];
  const float* bhh_rh = (const float*)d_in[4];
  const float* wih_ra = (const float*)d_in[5];
  const float* whh_ra = (const float*)d_in[6];
  const float* bih_ra = (const float*)d_in[7];
  const float* bhh_ra = (const float*)d_in[8];
  const float* wih_lh = (const float*)d_in[9];
  const float* whh_lh = (const float*)d_in[10];
  const float* bih_lh = (const float*)d_in[11];
  const float* bhh_lh = (const float*)d_in[12];
  const float* wih_la = (const float*)d_in[13];
  const float* whh_la = (const float*)d_in[14];
  const float* bih_la = (const float*)d_in[15];
  const float* bhh_la = (const float*)d_in[16];
  const float* att_w = (const float*)d_in[17];
  const float* fc_w = (const float*)d_in[18];
  const float* fc_b = (const float*)d_in[19];

  // ws layout (~65.2 MB)
  char* p = (char*)d_ws;
  float* combined = (float*)p;                      p += (size_t)BATCH * TLEN * HID * 4;  // 50,331,648
  unsigned short* fHR = (unsigned short*)p;         p += (size_t)4 * TLEN * 32 * 48 * 2;  // 6,291,456
  unsigned short* fHL = (unsigned short*)p;         p += (size_t)4 * TLEN * 32 * 48 * 2;
  unsigned short* fAR = (unsigned short*)p;         p += (size_t)2 * TLEN * 64 * 8 * 2;   // 1,048,576
  unsigned short* fAL = (unsigned short*)p;         p += (size_t)2 * TLEN * 64 * 8 * 2;
  unsigned short* bt_rh = (unsigned short*)p;       p += 256 * 128 * 2;
  unsigned short* bt_lh = (unsigned short*)p;       p += 256 * 128 * 2;
  unsigned short* bt_ra = (unsigned short*)p;       p += 128 * 64 * 2;
  unsigned short* bt_la = (unsigned short*)p;

  prep_kernel<<<dim3((BATCH * TLEN + 255) / 256), 256, 0, stream>>>(x, fHR, fHL, fAR, fAL);
  pack_kernel<<<dim3(4), 256, 0, stream>>>(
      wih_rh, whh_rh, wih_ra, whh_ra, wih_lh, whh_lh, wih_la, whh_la,
      bt_rh, bt_ra, bt_lh, bt_la);
  lstm_kernel<<<dim3(12), 512, 0, stream>>>(
      fHR, fHL, fAR, fAL, bt_rh, bt_ra, bt_lh, bt_la,
      bih_rh, bhh_rh, bih_ra, bhh_ra, bih_lh, bhh_lh, bih_la, bhh_la,
      combined);
  attn_kernel<<<dim3(BATCH), 512, 0, stream>>>(combined, att_w, fc_w, fc_b, (float*)d_out);
}

// Round 7
// 559.497 us; speedup vs baseline: 1.7305x; 1.7305x over previous
//
#include <hip/hip_runtime.h>
#include <math.h>

#define BATCH 128
#define TLEN 512
#define XF 266
#define HID 192
#define NC 250

typedef __attribute__((ext_vector_type(8))) short short8;
typedef __attribute__((ext_vector_type(4))) float float4v;

// fp32 -> bf16 (RNE)
__device__ __forceinline__ unsigned short f2bf(float f) {
  unsigned u = __float_as_uint(f);
  u += 0x7FFF + ((u >> 16) & 1);
  return (unsigned short)(u >> 16);
}

__device__ __forceinline__ float fast_sigmoid(float x) {
  float t = __expf(-x);
  return __builtin_amdgcn_rcpf(1.f + t);
}
// tanh(x) = 2*sigmoid(2x)-1
__device__ __forceinline__ float fast_tanh(float x) {
  float t = __expf(-2.f * x);
  return fmaf(2.f, __builtin_amdgcn_rcpf(1.f + t), -1.f);
}

// LDS-only barrier: does NOT drain vmcnt (global stores/loads keep flying).
__device__ __forceinline__ void lds_barrier() {
  asm volatile("s_waitcnt lgkmcnt(0)\n\ts_barrier" ::: "memory");
}

// ---------------- K1: feature prep -> per-LSTM padded bf16 layouts --------
// featH*: [tile8][t512][m16][48]  (42 real + 6 zero)
// featA*: [tile4][t512][m32][8]   (6 real + 2 zero)

__device__ __forceinline__ void norm_hand(const float* __restrict__ xp,
                                          unsigned short* __restrict__ fp,
                                          int p0, int refp) {
  float rx = xp[2 * refp], ry = xp[2 * refp + 1];
  float px[21], py[21];
  float minx = 1e30f, maxx = -1e30f, miny = 1e30f, maxy = -1e30f;
#pragma unroll
  for (int i = 0; i < 21; ++i) {
    float ax = xp[2 * (p0 + i)] - rx;
    float ay = xp[2 * (p0 + i) + 1] - ry;
    px[i] = ax; py[i] = ay;
    minx = fminf(minx, ax); maxx = fmaxf(maxx, ax);
    miny = fminf(miny, ay); maxy = fmaxf(maxy, ay);
  }
  float s = fmaxf(maxx - minx, maxy - miny);
  if (s == 0.f) s = 1.f;
  float inv = 1.f / s;
#pragma unroll
  for (int i = 0; i < 21; ++i) {
    fp[2 * i] = f2bf(px[i] * inv);
    fp[2 * i + 1] = f2bf(py[i] * inv);
  }
  fp[42] = 0; fp[43] = 0; fp[44] = 0; fp[45] = 0; fp[46] = 0; fp[47] = 0;
}

__device__ __forceinline__ void norm_arm(const float* __restrict__ xp,
                                         unsigned short* __restrict__ fp,
                                         int a, int b, int c) {
  float rx = xp[0], ry = xp[1];
  float x0 = xp[2 * a] - rx, y0 = xp[2 * a + 1] - ry;
  float x1 = xp[2 * b] - rx, y1 = xp[2 * b + 1] - ry;
  float x2 = xp[2 * c] - rx, y2 = xp[2 * c + 1] - ry;
  float w = fmaxf(fmaxf(x0, x1), x2) - fminf(fminf(x0, x1), x2);
  float h = fmaxf(fmaxf(y0, y1), y2) - fminf(fminf(y0, y1), y2);
  float s = fmaxf(w, h);
  if (s == 0.f) s = 1.f;
  float inv = 1.f / s;
  fp[0] = f2bf(x0 * inv); fp[1] = f2bf(y0 * inv);
  fp[2] = f2bf(x1 * inv); fp[3] = f2bf(y1 * inv);
  fp[4] = f2bf(x2 * inv); fp[5] = f2bf(y2 * inv);
  fp[6] = 0; fp[7] = 0;
}

__global__ __launch_bounds__(256) void prep_kernel(
    const float* __restrict__ x,
    unsigned short* __restrict__ fHR, unsigned short* __restrict__ fHL,
    unsigned short* __restrict__ fAR, unsigned short* __restrict__ fAL) {
  int idx = blockIdx.x * 256 + threadIdx.x;
  if (idx >= BATCH * TLEN) return;
  int b = idx >> 9, t = idx & 511;
  const float* xp = x + (size_t)idx * XF;
  size_t hoff = (((size_t)(b >> 4) * TLEN + t) * 16 + (b & 15)) * 48;
  size_t aoff = (((size_t)(b >> 5) * TLEN + t) * 32 + (b & 31)) * 8;
  norm_hand(xp, fHR + hoff, 112, 10);  // right hand, ref pt 10
  norm_hand(xp, fHL + hoff, 91, 9);    // left hand, ref pt 9
  norm_arm (xp, fAR + aoff, 6, 8, 10); // right arm
  norm_arm (xp, fAL + aoff, 5, 7, 9);  // left arm
}

// ---------------- K1b: weight packing -> bf16 B^T [G][K] ------------------
// Hands K=128 = [wih(42)|0(22)|whh(64)]; Arms K=64 = [wih(6)|0(26)|whh(32)]

__global__ __launch_bounds__(256) void pack_kernel(
    const float* __restrict__ wi_rh, const float* __restrict__ wh_rh,
    const float* __restrict__ wi_ra, const float* __restrict__ wh_ra,
    const float* __restrict__ wi_lh, const float* __restrict__ wh_lh,
    const float* __restrict__ wi_la, const float* __restrict__ wh_la,
    unsigned short* __restrict__ bt_rh, unsigned short* __restrict__ bt_ra,
    unsigned short* __restrict__ bt_lh, unsigned short* __restrict__ bt_la) {
  int blk = blockIdx.x, tid = threadIdx.x;
  if (blk == 0) {
    for (int i = tid; i < 256 * 128; i += 256) {
      int g = i >> 7, k = i & 127;
      float v = (k < 42) ? wi_rh[g * 42 + k] : (k < 64 ? 0.f : wh_rh[g * 64 + (k - 64)]);
      bt_rh[i] = f2bf(v);
    }
  } else if (blk == 1) {
    for (int i = tid; i < 256 * 128; i += 256) {
      int g = i >> 7, k = i & 127;
      float v = (k < 42) ? wi_lh[g * 42 + k] : (k < 64 ? 0.f : wh_lh[g * 64 + (k - 64)]);
      bt_lh[i] = f2bf(v);
    }
  } else if (blk == 2) {
    for (int i = tid; i < 128 * 64; i += 256) {
      int g = i >> 6, k = i & 63;
      float v = (k < 6) ? wi_ra[g * 6 + k] : (k < 32 ? 0.f : wh_ra[g * 32 + (k - 32)]);
      bt_ra[i] = f2bf(v);
    }
  } else {
    for (int i = tid; i < 128 * 64; i += 256) {
      int g = i >> 6, k = i & 63;
      float v = (k < 6) ? wi_la[g * 6 + k] : (k < 32 ? 0.f : wh_la[g * 32 + (k - 32)]);
      bt_la[i] = f2bf(v);
    }
  }
}

// ---------------- K2: MFMA LSTM recurrence --------------------------------
// R5 shape: 24 blocks x 256 threads (4 waves, 1 wave/SIMD). NEW in R7:
// 2-step-deep xf prefetch pipeline — the global load for slice t+1 is issued
// at the start of step t-1 (held in registers one full step), so HBM/LLC
// latency (~500-900 cyc) has ~2 steps to complete instead of <1.
// A row (hands, STR=136): [x 0..47 | 0 48..63 | h 64..127]  (16B-aligned rows)
// A row (arms,  STR=72):  [x 0..7  | 0 8..31  | h 32..63]
// Double-buffered, ONE lds-only barrier/step (no vmcnt drain).

template <int H, int CH, int STR, int MB, int SCH>
__device__ __forceinline__ void lstm_core(
    unsigned short* __restrict__ Ab0, unsigned short* __restrict__ Ab1,
    const unsigned short* __restrict__ Bt,
    const float* __restrict__ bi, const float* __restrict__ bh,
    const unsigned short* __restrict__ featp,
    float* __restrict__ comb,   // combined + coff
    int b0, int mrow0, int j0) {
  constexpr int K = CH * 32;
  constexpr int HOFF = K - H;
  constexpr int XSH = MB * SCH * 8;  // shorts per t-slice
  int tid = threadIdx.x;
  int lane = tid & 63, n = lane & 15, quad = lane >> 4;

  // B fragments + bias (loaded once; intended register/AGPR-resident)
  short8 Vb[4][CH];
  float bias[4];
#pragma unroll
  for (int q = 0; q < 4; ++q) {
    int g = q * H + j0 + n;
    bias[q] = bi[g] + bh[g];
#pragma unroll
    for (int c = 0; c < CH; ++c)
      Vb[q][c] = *(const short8*)(Bt + (size_t)g * K + c * 32 + quad * 8);
  }

  // zero both buffers (pads + initial h=0), stage x_0 into buf0,
  // and issue the load for slice t=1 (held in xva until end of step 0).
  for (int i = tid; i < MB * STR; i += 256) { Ab0[i] = 0; Ab1[i] = 0; }
  bool st = tid < MB * SCH;
  int sm = tid / SCH, sc8 = tid % SCH;
  unsigned short* xd0 = Ab0 + sm * STR + sc8 * 8;
  unsigned short* xd1 = Ab1 + sm * STR + sc8 * 8;
  const unsigned short* fp = featp + tid * 8;
  short8 xva;
  if (st) {
    *(short8*)xd0 = *(const short8*)fp;      // t=0
    xva = *(const short8*)(fp + XSH);        // t=1 (in flight)
  }
  fp += 2 * (size_t)XSH;                      // -> t=2 slice
  float4v cc = {0.f, 0.f, 0.f, 0.f};
  __syncthreads();

  const unsigned short* ard0 = Ab0 + (mrow0 + n) * STR;
  const unsigned short* ard1 = Ab1 + (mrow0 + n) * STR;
  unsigned short* hw0 = Ab0 + (mrow0 + quad * 4) * STR + HOFF + j0 + n;
  unsigned short* hw1 = Ab1 + (mrow0 + quad * 4) * STR + HOFF + j0 + n;

  float* cp0 = comb + ((size_t)(b0 + mrow0 + quad * 4 + 0) * TLEN) * HID + j0 + n;
  float* cp1 = comb + ((size_t)(b0 + mrow0 + quad * 4 + 1) * TLEN) * HID + j0 + n;
  float* cp2 = comb + ((size_t)(b0 + mrow0 + quad * 4 + 2) * TLEN) * HID + j0 + n;
  float* cp3 = comb + ((size_t)(b0 + mrow0 + quad * 4 + 3) * TLEN) * HID + j0 + n;

  for (int t = 0; t < TLEN; ++t) {
    int par = t & 1;
    // issue load for slice t+2 (consumed at end of step t+1)
    short8 xvb;
    bool pf2 = st && (t + 2 < TLEN);
    if (pf2) xvb = *(const short8*)fp;
    fp += XSH;

    const unsigned short* ard = par ? ard1 : ard0;
    short8 Va[CH];
#pragma unroll
    for (int c = 0; c < CH; ++c)
      Va[c] = *(const short8*)(ard + c * 32 + quad * 8);

    float4v acc[4];
#pragma unroll
    for (int q = 0; q < 4; ++q) {
      acc[q] = (float4v){bias[q], bias[q], bias[q], bias[q]};
#pragma unroll
      for (int c = 0; c < CH; ++c)
        acc[q] = __builtin_amdgcn_mfma_f32_16x16x32_bf16(Va[c], Vb[q][c], acc[q], 0, 0, 0);
    }

    unsigned short* hw = par ? hw0 : hw1;  // write the buffer we'll read next
#pragma unroll
    for (int r = 0; r < 4; ++r) {
      float gi = fast_sigmoid(acc[0][r]);
      float gf = fast_sigmoid(acc[1][r]);
      float gg = fast_tanh(acc[2][r]);
      float go = fast_sigmoid(acc[3][r]);
      float cv = fmaf(gf, cc[r], gi * gg);
      cc[r] = cv;
      float h = go * fast_tanh(cv);
      hw[r * STR] = f2bf(h);
      if (r == 0) { *cp0 = h; cp0 += HID; }
      else if (r == 1) { *cp1 = h; cp1 += HID; }
      else if (r == 2) { *cp2 = h; cp2 += HID; }
      else { *cp3 = h; cp3 += HID; }
    }

    // write slice t+1 (loaded a full step ago) into next step's buffer
    if (st && t + 1 < TLEN) *(short8*)(par ? xd0 : xd1) = xva;
    xva = xvb;
    lds_barrier();
  }
}

__global__ __launch_bounds__(256, 1) void lstm_kernel(
    const unsigned short* __restrict__ fHR, const unsigned short* __restrict__ fHL,
    const unsigned short* __restrict__ fAR, const unsigned short* __restrict__ fAL,
    const unsigned short* __restrict__ bt_rh, const unsigned short* __restrict__ bt_ra,
    const unsigned short* __restrict__ bt_lh, const unsigned short* __restrict__ bt_la,
    const float* __restrict__ b0i, const float* __restrict__ b0h,
    const float* __restrict__ b1i, const float* __restrict__ b1h,
    const float* __restrict__ b2i, const float* __restrict__ b2h,
    const float* __restrict__ b3i, const float* __restrict__ b3h,
    float* __restrict__ combined) {
  __shared__ __align__(16) unsigned short A0[2304];
  __shared__ __align__(16) unsigned short A1[2304];
  int blk = blockIdx.x;
  int wave = threadIdx.x >> 6;
  if (blk < 8) {          // right hand: H=64, batches [16*blk,+16)
    lstm_core<64, 4, 136, 16, 6>(A0, A1, bt_rh, b0i, b0h,
                                 fHR + (size_t)blk * TLEN * 768,
                                 combined + 0, blk * 16, 0, 16 * wave);
  } else if (blk < 16) {  // left hand
    int tl = blk - 8;
    lstm_core<64, 4, 136, 16, 6>(A0, A1, bt_lh, b2i, b2h,
                                 fHL + (size_t)tl * TLEN * 768,
                                 combined + 96, tl * 16, 0, 16 * wave);
  } else if (blk < 20) {  // right arm: H=32, batches [32*(blk-16),+32)
    int tl = blk - 16;
    lstm_core<32, 2, 72, 32, 1>(A0, A1, bt_ra, b1i, b1h,
                                fAR + (size_t)tl * TLEN * 256,
                                combined + 64, tl * 32, 16 * (wave >> 1), 16 * (wave & 1));
  } else {                // left arm
    int tl = blk - 20;
    lstm_core<32, 2, 72, 32, 1>(A0, A1, bt_la, b3i, b3h,
                                fAL + (size_t)tl * TLEN * 256,
                                combined + 160, tl * 32, 16 * (wave >> 1), 16 * (wave & 1));
  }
}

// ---------------- K3: attention + FC (512 threads) ------------------------

__global__ __launch_bounds__(512) void attn_kernel(const float* __restrict__ combined,
                                                   const float* __restrict__ att_w,
                                                   const float* __restrict__ fc_w,
                                                   const float* __restrict__ fc_b,
                                                   float* __restrict__ dout) {
  __shared__ float sc[TLEN];
  __shared__ float aw[HID];
  __shared__ float pctx[8][HID];
  __shared__ float ctx[HID];
  __shared__ float red[8];
  int b = blockIdx.x, tid = threadIdx.x;
  int lane = tid & 63, wave = tid >> 6;
  const float* cb = combined + (size_t)b * TLEN * HID;
  if (tid < HID) aw[tid] = att_w[tid];
  __syncthreads();
  float a0 = aw[lane], a1 = aw[lane + 64], a2 = aw[lane + 128];

  // scores: each wave 64 t's, 2 in flight
  int t0 = wave * 64;
  for (int t = t0; t < t0 + 64; t += 2) {
    const float* r0 = cb + (size_t)t * HID;
    const float* r1 = r0 + HID;
    float p0 = a0 * r0[lane] + a1 * r0[lane + 64] + a2 * r0[lane + 128];
    float p1 = a0 * r1[lane] + a1 * r1[lane + 64] + a2 * r1[lane + 128];
#pragma unroll
    for (int o = 32; o; o >>= 1) {
      p0 += __shfl_xor(p0, o, 64);
      p1 += __shfl_xor(p1, o, 64);
    }
    if (lane == 0) { sc[t] = p0; sc[t + 1] = p1; }
  }
  __syncthreads();

  // softmax: one t per thread
  float e = sc[tid];
  float lmax = e;
#pragma unroll
  for (int o = 32; o; o >>= 1) lmax = fmaxf(lmax, __shfl_xor(lmax, o, 64));
  if (lane == 0) red[wave] = lmax;
  __syncthreads();
  float m = red[0];
#pragma unroll
  for (int w = 1; w < 8; ++w) m = fmaxf(m, red[w]);
  __syncthreads();
  float ex = __expf(e - m);
  float ls = ex;
#pragma unroll
  for (int o = 32; o; o >>= 1) ls += __shfl_xor(ls, o, 64);
  if (lane == 0) red[wave] = ls;
  __syncthreads();
  float S = red[0];
#pragma unroll
  for (int w = 1; w < 8; ++w) S += red[w];
  float wgt = ex / S;
  sc[tid] = wgt;
  dout[BATCH * NC + b * TLEN + tid] = wgt;  // weights output (B,T,1)
  __syncthreads();

  // context: coalesced (lanes = h), 8 t-groups reduced via LDS
#pragma unroll
  for (int p = 0; p < 3; ++p) {
    int h = p * 64 + lane;
    float c0 = 0.f, c1 = 0.f, c2 = 0.f, c3 = 0.f;
    for (int t = t0; t < t0 + 64; t += 4) {
      c0 += sc[t] * cb[(size_t)t * HID + h];
      c1 += sc[t + 1] * cb[(size_t)(t + 1) * HID + h];
      c2 += sc[t + 2] * cb[(size_t)(t + 2) * HID + h];
      c3 += sc[t + 3] * cb[(size_t)(t + 3) * HID + h];
    }
    pctx[wave][h] = (c0 + c1) + (c2 + c3);
  }
  __syncthreads();
  if (tid < HID) {
    float s = pctx[0][tid];
#pragma unroll
    for (int w = 1; w < 8; ++w) s += pctx[w][tid];
    ctx[tid] = s;
  }
  __syncthreads();

  // FC
  if (tid < NC) {
    const float* wr = fc_w + (size_t)tid * HID;
    float s0 = fc_b[tid], s1 = 0.f, s2 = 0.f, s3 = 0.f;
#pragma unroll
    for (int h = 0; h < HID; h += 4) {
      s0 += ctx[h] * wr[h];
      s1 += ctx[h + 1] * wr[h + 1];
      s2 += ctx[h + 2] * wr[h + 2];
      s3 += ctx[h + 3] * wr[h + 3];
    }
    dout[b * NC + tid] = (s0 + s1) + (s2 + s3);  // logits (B,250)
  }
}

// ---------------- launcher ----------------

extern "C" void kernel_launch(void* const* d_in, const int* in_sizes, int n_in,
                              void* d_out, int out_size, void* d_ws, size_t ws_size,
                              hipStream_t stream) {
  const float* x = (const float*)d_in[0];
  const float* wih_rh = (const float*)d_in[1];
  const float* whh_rh = (const float*)d_in[2];
  const float* bih_rh = (const float*)d_in[3];
  const float* bhh_rh = (const float*)d_in[4];
  const float* wih_ra = (const float*)d_in[5];
  const float* whh_ra = (const float*)d_in[6];
  const float* bih_ra = (const float*)d_in[7];
  const float* bhh_ra = (const float*)d_in[8];
  const float* wih_lh = (const float*)d_in[9];
  const float* whh_lh = (const float*)d_in[10];
  const float* bih_lh = (const float*)d_in[11];
  const float* bhh_lh = (const float*)d_in[12];
  const float* wih_la = (const float*)d_in[13];
  const float* whh_la = (const float*)d_in[14];
  const float* bih_la = (const float*)d_in[15];
  const float* bhh_la = (const float*)d_in[16];
  const float* att_w = (const float*)d_in[17];
  const float* fc_w = (const float*)d_in[18];
  const float* fc_b = (const float*)d_in[19];

  // ws layout (~65.2 MB)
  char* p = (char*)d_ws;
  float* combined = (float*)p;                      p += (size_t)BATCH * TLEN * HID * 4;  // 50,331,648
  unsigned short* fHR = (unsigned short*)p;         p += (size_t)8 * TLEN * 16 * 48 * 2;  // 6,291,456
  unsigned short* fHL = (unsigned short*)p;         p += (size_t)8 * TLEN * 16 * 48 * 2;
  unsigned short* fAR = (unsigned short*)p;         p += (size_t)4 * TLEN * 32 * 8 * 2;   // 1,048,576
  unsigned short* fAL = (unsigned short*)p;         p += (size_t)4 * TLEN * 32 * 8 * 2;
  unsigned short* bt_rh = (unsigned short*)p;       p += 256 * 128 * 2;
  unsigned short* bt_lh = (unsigned short*)p;       p += 256 * 128 * 2;
  unsigned short* bt_ra = (unsigned short*)p;       p += 128 * 64 * 2;
  unsigned short* bt_la = (unsigned short*)p;

  prep_kernel<<<dim3((BATCH * TLEN + 255) / 256), 256, 0, stream>>>(x, fHR, fHL, fAR, fAL);
  pack_kernel<<<dim3(4), 256, 0, stream>>>(
      wih_rh, whh_rh, wih_ra, whh_ra, wih_lh, whh_lh, wih_la, whh_la,
      bt_rh, bt_ra, bt_lh, bt_la);
  lstm_kernel<<<dim3(24), 256, 0, stream>>>(
      fHR, fHL, fAR, fAL, bt_rh, bt_ra, bt_lh, bt_la,
      bih_rh, bhh_rh, bih_ra, bhh_ra, bih_lh, bhh_lh, bih_la, bhh_la,
      combined);
  attn_kernel<<<dim3(BATCH), 512, 0, stream>>>(combined, att_w, fc_w, fc_b, (float*)d_out);
}

// Round 8
// 533.020 us; speedup vs baseline: 1.8164x; 1.0497x over previous
//
#include <hip/hip_runtime.h>
#include <math.h>

#define BATCH 128
#define TLEN 512
#define XF 266
#define HID 192
#define NC 250

typedef __attribute__((ext_vector_type(8))) short short8;
typedef __attribute__((ext_vector_type(4))) float float4v;

// fp32 -> bf16 (RNE)
__device__ __forceinline__ unsigned short f2bf(float f) {
  unsigned u = __float_as_uint(f);
  u += 0x7FFF + ((u >> 16) & 1);
  return (unsigned short)(u >> 16);
}
__device__ __forceinline__ float bf2f(unsigned short s) {
  return __uint_as_float(((unsigned)s) << 16);
}

__device__ __forceinline__ float fast_sigmoid(float x) {
  float t = __expf(-x);
  return __builtin_amdgcn_rcpf(1.f + t);
}
__device__ __forceinline__ float fast_tanh(float x) {
  float t = __expf(-2.f * x);
  return fmaf(2.f, __builtin_amdgcn_rcpf(1.f + t), -1.f);
}

// LDS-only barrier: does NOT drain vmcnt.
__device__ __forceinline__ void lds_barrier() {
  asm volatile("s_waitcnt lgkmcnt(0)\n\ts_barrier" ::: "memory");
}

// ---------------- K1: feature prep --------------------------------------
// Hands: [tile8][t][m16][HS]  (HS=64 hoist-mode, zeros 42..63; HS=48 fallback)
// Arms:  [tile4][t][m32][8]   (6 real + 2 zero)

__device__ __forceinline__ void norm_hand(const float* __restrict__ xp,
                                          unsigned short* __restrict__ fp,
                                          int p0, int refp, int hs) {
  float rx = xp[2 * refp], ry = xp[2 * refp + 1];
  float px[21], py[21];
  float minx = 1e30f, maxx = -1e30f, miny = 1e30f, maxy = -1e30f;
#pragma unroll
  for (int i = 0; i < 21; ++i) {
    float ax = xp[2 * (p0 + i)] - rx;
    float ay = xp[2 * (p0 + i) + 1] - ry;
    px[i] = ax; py[i] = ay;
    minx = fminf(minx, ax); maxx = fmaxf(maxx, ax);
    miny = fminf(miny, ay); maxy = fmaxf(maxy, ay);
  }
  float s = fmaxf(maxx - minx, maxy - miny);
  if (s == 0.f) s = 1.f;
  float inv = 1.f / s;
#pragma unroll
  for (int i = 0; i < 21; ++i) {
    fp[2 * i] = f2bf(px[i] * inv);
    fp[2 * i + 1] = f2bf(py[i] * inv);
  }
  for (int i = 42; i < hs; ++i) fp[i] = 0;
}

__device__ __forceinline__ void norm_arm(const float* __restrict__ xp,
                                         unsigned short* __restrict__ fp,
                                         int a, int b, int c) {
  float rx = xp[0], ry = xp[1];
  float x0 = xp[2 * a] - rx, y0 = xp[2 * a + 1] - ry;
  float x1 = xp[2 * b] - rx, y1 = xp[2 * b + 1] - ry;
  float x2 = xp[2 * c] - rx, y2 = xp[2 * c + 1] - ry;
  float w = fmaxf(fmaxf(x0, x1), x2) - fminf(fminf(x0, x1), x2);
  float h = fmaxf(fmaxf(y0, y1), y2) - fminf(fminf(y0, y1), y2);
  float s = fmaxf(w, h);
  if (s == 0.f) s = 1.f;
  float inv = 1.f / s;
  fp[0] = f2bf(x0 * inv); fp[1] = f2bf(y0 * inv);
  fp[2] = f2bf(x1 * inv); fp[3] = f2bf(y1 * inv);
  fp[4] = f2bf(x2 * inv); fp[5] = f2bf(y2 * inv);
  fp[6] = 0; fp[7] = 0;
}

__global__ __launch_bounds__(256) void prep_kernel(
    const float* __restrict__ x,
    unsigned short* __restrict__ fHR, unsigned short* __restrict__ fHL,
    unsigned short* __restrict__ fAR, unsigned short* __restrict__ fAL,
    int hs) {
  int idx = blockIdx.x * 256 + threadIdx.x;
  if (idx >= BATCH * TLEN) return;
  int b = idx >> 9, t = idx & 511;
  const float* xp = x + (size_t)idx * XF;
  size_t hoff = (((size_t)(b >> 4) * TLEN + t) * 16 + (b & 15)) * hs;
  size_t aoff = (((size_t)(b >> 5) * TLEN + t) * 32 + (b & 31)) * 8;
  norm_hand(xp, fHR + hoff, 112, 10, hs);  // right hand, ref pt 10
  norm_hand(xp, fHL + hoff, 91, 9, hs);    // left hand, ref pt 9
  norm_arm (xp, fAR + aoff, 6, 8, 10);     // right arm
  norm_arm (xp, fAL + aoff, 5, 7, 9);      // left arm
}

// ---------------- K1b: weight packing -----------------------------------
// mode 1 (hoist): btA = Wih^T [256][64] (k<42), btH = Whh^T [256][64]
// mode 0 (fallback): btA = [256][128] = [wih42|0|whh64]
// arms (both): btArm [128][64] = [wih6|0|whh32]

__global__ __launch_bounds__(256) void pack_kernel(
    int mode,
    const float* __restrict__ wi_rh, const float* __restrict__ wh_rh,
    const float* __restrict__ wi_ra, const float* __restrict__ wh_ra,
    const float* __restrict__ wi_lh, const float* __restrict__ wh_lh,
    const float* __restrict__ wi_la, const float* __restrict__ wh_la,
    unsigned short* __restrict__ btA_r, unsigned short* __restrict__ btA_l,
    unsigned short* __restrict__ btH_r, unsigned short* __restrict__ btH_l,
    unsigned short* __restrict__ btArm_r, unsigned short* __restrict__ btArm_l) {
  int blk = blockIdx.x, tid = threadIdx.x;
  if (blk < 2) {
    const float* wi = blk ? wi_lh : wi_rh;
    const float* wh = blk ? wh_lh : wh_rh;
    unsigned short* dst = blk ? btA_l : btA_r;
    if (mode) {
      for (int i = tid; i < 256 * 64; i += 256) {
        int g = i >> 6, k = i & 63;
        dst[i] = f2bf(k < 42 ? wi[g * 42 + k] : 0.f);
      }
    } else {
      for (int i = tid; i < 256 * 128; i += 256) {
        int g = i >> 7, k = i & 127;
        float v = (k < 42) ? wi[g * 42 + k] : (k < 64 ? 0.f : wh[g * 64 + (k - 64)]);
        dst[i] = f2bf(v);
      }
    }
  } else if (blk < 4) {
    if (mode) {
      const float* wh = (blk == 3) ? wh_lh : wh_rh;
      unsigned short* dst = (blk == 3) ? btH_l : btH_r;
      for (int i = tid; i < 256 * 64; i += 256) dst[i] = f2bf(wh[i]);
    }
  } else {
    const float* wi = (blk == 5) ? wi_la : wi_ra;
    const float* wh = (blk == 5) ? wh_la : wh_ra;
    unsigned short* dst = (blk == 5) ? btArm_l : btArm_r;
    for (int i = tid; i < 128 * 64; i += 256) {
      int g = i >> 6, k = i & 63;
      float v = (k < 6) ? wi[g * 6 + k] : (k < 32 ? 0.f : wh[g * 32 + (k - 32)]);
      dst[i] = f2bf(v);
    }
  }
}

// ---------------- K1c: input-projection pre-GEMM (hoist mode) ------------
// pre[(tile*512+t)*4096 + jg*1024 + n*64 + quad*16 + q*4 + r] (bf16), with
// bias folded. 256 blocks = (lr, tile8, tc16); wave = q; 32 t per block.

__global__ __launch_bounds__(256, 1) void pregemm_kernel(
    const unsigned short* __restrict__ f64R, const unsigned short* __restrict__ f64L,
    const unsigned short* __restrict__ btiR, const unsigned short* __restrict__ btiL,
    const float* __restrict__ biR, const float* __restrict__ bhR,
    const float* __restrict__ biL, const float* __restrict__ bhL,
    unsigned short* __restrict__ preR, unsigned short* __restrict__ preL) {
  int bx = blockIdx.x;
  int lr = bx >> 7, tile = (bx >> 4) & 7, tc = bx & 15;
  const unsigned short* f64 = lr ? f64L : f64R;
  const unsigned short* bti = lr ? btiL : btiR;
  const float* bi = lr ? biL : biR;
  const float* bh = lr ? bhL : bhR;
  unsigned short* pre = lr ? preL : preR;
  int tid = threadIdx.x, lane = tid & 63;
  int q = tid >> 6, n = lane & 15, quad = lane >> 4;

  short8 Vb[4][2];
  float bias[4];
#pragma unroll
  for (int jg = 0; jg < 4; ++jg) {
    int g = q * 64 + jg * 16 + n;
    bias[jg] = bi[g] + bh[g];
#pragma unroll
    for (int c = 0; c < 2; ++c)
      Vb[jg][c] = *(const short8*)(bti + (size_t)g * 64 + c * 32 + quad * 8);
  }

  for (int i = 0; i < 32; ++i) {
    int t = tc * 32 + i;
    const unsigned short* ap = f64 + ((size_t)(tile * 512 + t) * 16 + n) * 64 + quad * 8;
    short8 Va0 = *(const short8*)ap;
    short8 Va1 = *(const short8*)(ap + 32);
    unsigned short* pb = pre + (size_t)(tile * 512 + t) * 4096 + n * 64 + quad * 16 + q * 4;
#pragma unroll
    for (int jg = 0; jg < 4; ++jg) {
      float4v acc = {bias[jg], bias[jg], bias[jg], bias[jg]};
      acc = __builtin_amdgcn_mfma_f32_16x16x32_bf16(Va0, Vb[jg][0], acc, 0, 0, 0);
      acc = __builtin_amdgcn_mfma_f32_16x16x32_bf16(Va1, Vb[jg][1], acc, 0, 0, 0);
      unsigned lo = (unsigned)f2bf(acc[0]) | ((unsigned)f2bf(acc[1]) << 16);
      unsigned hi = (unsigned)f2bf(acc[2]) | ((unsigned)f2bf(acc[3]) << 16);
      uint2 v; v.x = lo; v.y = hi;
      *(uint2*)(pb + (size_t)jg * 1024) = v;
    }
  }
}

// ---------------- K2: MFMA LSTM recurrence --------------------------------
// HOIST hands: A rows = h only (K=64, CH=2, STR=72), acc-init from pre
// (2-deep prefetched). Fallback hands: R7 structure (K=128, CH=4, STR=136).
// Arms (both): K=64 rows [x8|0|h32], inline staging.
// comb written via LDS re-read (coalesced dwordx4), lagged one step.

template <int H, int CH, int STR, int MB, int SCH, int HOFF, bool HOIST>
__device__ __forceinline__ void lstm_core(
    unsigned short* __restrict__ Ab0, unsigned short* __restrict__ Ab1,
    const unsigned short* __restrict__ Bt,
    const float* __restrict__ bi, const float* __restrict__ bh,
    const unsigned short* __restrict__ featp,   // !HOIST only
    const unsigned short* __restrict__ prep_,   // HOIST only (tile base)
    float* __restrict__ combbase,               // combined + coff
    int b0, int mrow0, int j0) {
  constexpr int K = CH * 32;
  constexpr int XSH = MB * SCH * 8;
  constexpr int JQ = H / 4;
  int tid = threadIdx.x;
  int lane = tid & 63, n = lane & 15, quad = lane >> 4;

  // B fragments (+bias if no pre)
  short8 Vb[4][CH];
  float bias[4];
#pragma unroll
  for (int q = 0; q < 4; ++q) {
    int g = q * H + j0 + n;
    if (!HOIST) bias[q] = bi[g] + bh[g];
#pragma unroll
    for (int c = 0; c < CH; ++c)
      Vb[q][c] = *(const short8*)(Bt + (size_t)g * K + c * 32 + quad * 8);
  }

  for (int i = tid; i < MB * STR; i += 256) { Ab0[i] = 0; Ab1[i] = 0; }

  // x staging (fallback/arms): 2-deep
  bool st = false;
  unsigned short *xd0 = nullptr, *xd1 = nullptr;
  const unsigned short* fp = nullptr;
  short8 xva;
  if (!HOIST) {
    st = tid < MB * SCH;
    int sm = tid / SCH, sc8 = tid % SCH;
    xd0 = Ab0 + sm * STR + sc8 * 8;
    xd1 = Ab1 + sm * STR + sc8 * 8;
    fp = featp + tid * 8;
    if (st) {
      *(short8*)xd0 = *(const short8*)fp;
      xva = *(const short8*)(fp + XSH);
    }
    fp += 2 * (size_t)XSH;
  }

  // pre prefetch (hoist): 2-deep
  const unsigned short* pp = nullptr;
  short8 pc0, pc1, pn0, pn1;
  if (HOIST) {
    pp = prep_ + (size_t)(j0 >> 4) * 1024 + n * 64 + quad * 16;
    pc0 = *(const short8*)pp;
    pc1 = *(const short8*)(pp + 8);
    pn0 = *(const short8*)(pp + 4096);
    pn1 = *(const short8*)(pp + 4096 + 8);
    pp += 2 * (size_t)4096;
  }

  float4v cc = {0.f, 0.f, 0.f, 0.f};
  __syncthreads();

  const unsigned short* ard0 = Ab0 + (mrow0 + n) * STR;
  const unsigned short* ard1 = Ab1 + (mrow0 + n) * STR;
  unsigned short* hw0 = Ab0 + (mrow0 + quad * 4) * STR + HOFF + j0 + n;
  unsigned short* hw1 = Ab1 + (mrow0 + quad * 4) * STR + HOFF + j0 + n;

  // comb flush mapping (block-wide, coalesced)
  int fm = tid / JQ, fjq = tid % JQ;
  const unsigned short* fl0 = Ab0 + fm * STR + HOFF + fjq * 4;
  const unsigned short* fl1 = Ab1 + fm * STR + HOFF + fjq * 4;
  float* cfp = combbase + ((size_t)(b0 + fm) * TLEN) * HID + fjq * 4;

  for (int t = 0; t < TLEN; ++t) {
    int par = t & 1;
    // issue staging/pre loads for t+2
    short8 xvb, pm0, pm1;
    if (!HOIST) {
      if (st && t + 2 < TLEN) xvb = *(const short8*)fp;
      fp += XSH;
    } else {
      if (t + 2 < TLEN) {
        pm0 = *(const short8*)pp;
        pm1 = *(const short8*)(pp + 8);
      }
      pp += 4096;
    }

    // flush h^{t-1} to combined (coalesced)
    if (t > 0) {
      const unsigned short* fl = par ? fl1 : fl0;
      uint2 hv = *(const uint2*)fl;
      float4v hf;
      hf[0] = __uint_as_float(hv.x << 16);
      hf[1] = __uint_as_float(hv.x & 0xffff0000u);
      hf[2] = __uint_as_float(hv.y << 16);
      hf[3] = __uint_as_float(hv.y & 0xffff0000u);
      *(float4v*)cfp = hf;
      cfp += HID;
    }

    // A fragments
    const unsigned short* ard = par ? ard1 : ard0;
    short8 Va[CH];
#pragma unroll
    for (int c = 0; c < CH; ++c)
      Va[c] = *(const short8*)(ard + c * 32 + quad * 8);

    // gates
    float4v acc[4];
    if (HOIST) {
#pragma unroll
      for (int r = 0; r < 4; ++r) {
        acc[0][r] = bf2f((unsigned short)pc0[r]);
        acc[1][r] = bf2f((unsigned short)pc0[4 + r]);
        acc[2][r] = bf2f((unsigned short)pc1[r]);
        acc[3][r] = bf2f((unsigned short)pc1[4 + r]);
      }
    } else {
#pragma unroll
      for (int q = 0; q < 4; ++q)
        acc[q] = (float4v){bias[q], bias[q], bias[q], bias[q]};
    }
#pragma unroll
    for (int q = 0; q < 4; ++q)
#pragma unroll
      for (int c = 0; c < CH; ++c)
        acc[q] = __builtin_amdgcn_mfma_f32_16x16x32_bf16(Va[c], Vb[q][c], acc[q], 0, 0, 0);

    // activations + state; h -> other LDS buffer (bf16)
    unsigned short* hw = par ? hw0 : hw1;
#pragma unroll
    for (int r = 0; r < 4; ++r) {
      float gi = fast_sigmoid(acc[0][r]);
      float gf = fast_sigmoid(acc[1][r]);
      float gg = fast_tanh(acc[2][r]);
      float go = fast_sigmoid(acc[3][r]);
      float cv = fmaf(gf, cc[r], gi * gg);
      cc[r] = cv;
      float h = go * fast_tanh(cv);
      hw[r * STR] = f2bf(h);
    }

    // rotate staging registers
    if (!HOIST) {
      if (st && t + 1 < TLEN) *(short8*)(par ? xd0 : xd1) = xva;
      xva = xvb;
    } else {
      pc0 = pn0; pc1 = pn1; pn0 = pm0; pn1 = pm1;
    }
    lds_barrier();
  }

  // final flush: h^{T-1} lives in buffer parity (TLEN&1)==0 -> Ab0
  {
    uint2 hv = *(const uint2*)fl0;
    float4v hf;
    hf[0] = __uint_as_float(hv.x << 16);
    hf[1] = __uint_as_float(hv.x & 0xffff0000u);
    hf[2] = __uint_as_float(hv.y << 16);
    hf[3] = __uint_as_float(hv.y & 0xffff0000u);
    *(float4v*)cfp = hf;
  }
}

__global__ __launch_bounds__(256, 1) void lstm_hoist(
    const unsigned short* __restrict__ fAR, const unsigned short* __restrict__ fAL,
    const unsigned short* __restrict__ btH_r, const unsigned short* __restrict__ btH_l,
    const unsigned short* __restrict__ btArm_r, const unsigned short* __restrict__ btArm_l,
    const unsigned short* __restrict__ preR, const unsigned short* __restrict__ preL,
    const float* __restrict__ b1i, const float* __restrict__ b1h,
    const float* __restrict__ b3i, const float* __restrict__ b3h,
    float* __restrict__ combined) {
  __shared__ __align__(16) unsigned short A0[2304];
  __shared__ __align__(16) unsigned short A1[2304];
  int blk = blockIdx.x;
  int wave = threadIdx.x >> 6;
  if (blk < 16) {           // hands: H=64, MB=16, h-only rows (STR=72)
    int lr = blk >> 3, tl = blk & 7;
    lstm_core<64, 2, 72, 16, 0, 0, true>(
        A0, A1, lr ? btH_l : btH_r, nullptr, nullptr, nullptr,
        (lr ? preL : preR) + (size_t)tl * 512 * 4096,
        combined + (lr ? 96 : 0), tl * 16, 0, wave * 16);
  } else {                  // arms: H=32, MB=32, rows [x8|0|h32] (STR=72)
    int a = blk - 16;
    int la = a >> 2, tl = a & 3;
    lstm_core<32, 2, 72, 32, 1, 32, false>(
        A0, A1, la ? btArm_l : btArm_r, la ? b3i : b1i, la ? b3h : b1h,
        (la ? fAL : fAR) + (size_t)tl * 512 * 256, nullptr,
        combined + (la ? 160 : 64), tl * 32, (wave >> 1) * 16, (wave & 1) * 16);
  }
}

__global__ __launch_bounds__(256, 1) void lstm_fb(
    const unsigned short* __restrict__ fHR, const unsigned short* __restrict__ fHL,
    const unsigned short* __restrict__ fAR, const unsigned short* __restrict__ fAL,
    const unsigned short* __restrict__ btA_r, const unsigned short* __restrict__ btA_l,
    const unsigned short* __restrict__ btArm_r, const unsigned short* __restrict__ btArm_l,
    const float* __restrict__ b0i, const float* __restrict__ b0h,
    const float* __restrict__ b1i, const float* __restrict__ b1h,
    const float* __restrict__ b2i, const float* __restrict__ b2h,
    const float* __restrict__ b3i, const float* __restrict__ b3h,
    float* __restrict__ combined) {
  __shared__ __align__(16) unsigned short A0[2304];
  __shared__ __align__(16) unsigned short A1[2304];
  int blk = blockIdx.x;
  int wave = threadIdx.x >> 6;
  if (blk < 16) {           // hands: K=128 rows [x48|0|h64] (STR=136)
    int lr = blk >> 3, tl = blk & 7;
    lstm_core<64, 4, 136, 16, 6, 64, false>(
        A0, A1, lr ? btA_l : btA_r, lr ? b2i : b0i, lr ? b2h : b0h,
        (lr ? fHL : fHR) + (size_t)tl * 512 * 768, nullptr,
        combined + (lr ? 96 : 0), tl * 16, 0, wave * 16);
  } else {
    int a = blk - 16;
    int la = a >> 2, tl = a & 3;
    lstm_core<32, 2, 72, 32, 1, 32, false>(
        A0, A1, la ? btArm_l : btArm_r, la ? b3i : b1i, la ? b3h : b1h,
        (la ? fAL : fAR) + (size_t)tl * 512 * 256, nullptr,
        combined + (la ? 160 : 64), tl * 32, (wave >> 1) * 16, (wave & 1) * 16);
  }
}

// ---------------- K3: attention + FC (512 threads) ------------------------

__global__ __launch_bounds__(512) void attn_kernel(const float* __restrict__ combined,
                                                   const float* __restrict__ att_w,
                                                   const float* __restrict__ fc_w,
                                                   const float* __restrict__ fc_b,
                                                   float* __restrict__ dout) {
  __shared__ float sc[TLEN];
  __shared__ float aw[HID];
  __shared__ float pctx[8][HID];
  __shared__ float ctx[HID];
  __shared__ float red[8];
  int b = blockIdx.x, tid = threadIdx.x;
  int lane = tid & 63, wave = tid >> 6;
  const float* cb = combined + (size_t)b * TLEN * HID;
  if (tid < HID) aw[tid] = att_w[tid];
  __syncthreads();
  float a0 = aw[lane], a1 = aw[lane + 64], a2 = aw[lane + 128];

  int t0 = wave * 64;
  for (int t = t0; t < t0 + 64; t += 2) {
    const float* r0 = cb + (size_t)t * HID;
    const float* r1 = r0 + HID;
    float p0 = a0 * r0[lane] + a1 * r0[lane + 64] + a2 * r0[lane + 128];
    float p1 = a0 * r1[lane] + a1 * r1[lane + 64] + a2 * r1[lane + 128];
#pragma unroll
    for (int o = 32; o; o >>= 1) {
      p0 += __shfl_xor(p0, o, 64);
      p1 += __shfl_xor(p1, o, 64);
    }
    if (lane == 0) { sc[t] = p0; sc[t + 1] = p1; }
  }
  __syncthreads();

  float e = sc[tid];
  float lmax = e;
#pragma unroll
  for (int o = 32; o; o >>= 1) lmax = fmaxf(lmax, __shfl_xor(lmax, o, 64));
  if (lane == 0) red[wave] = lmax;
  __syncthreads();
  float m = red[0];
#pragma unroll
  for (int w = 1; w < 8; ++w) m = fmaxf(m, red[w]);
  __syncthreads();
  float ex = __expf(e - m);
  float ls = ex;
#pragma unroll
  for (int o = 32; o; o >>= 1) ls += __shfl_xor(ls, o, 64);
  if (lane == 0) red[wave] = ls;
  __syncthreads();
  float S = red[0];
#pragma unroll
  for (int w = 1; w < 8; ++w) S += red[w];
  float wgt = ex / S;
  sc[tid] = wgt;
  dout[BATCH * NC + b * TLEN + tid] = wgt;  // weights (B,T,1)
  __syncthreads();

#pragma unroll
  for (int p = 0; p < 3; ++p) {
    int h = p * 64 + lane;
    float c0 = 0.f, c1 = 0.f, c2 = 0.f, c3 = 0.f;
    for (int t = t0; t < t0 + 64; t += 4) {
      c0 += sc[t] * cb[(size_t)t * HID + h];
      c1 += sc[t + 1] * cb[(size_t)(t + 1) * HID + h];
      c2 += sc[t + 2] * cb[(size_t)(t + 2) * HID + h];
      c3 += sc[t + 3] * cb[(size_t)(t + 3) * HID + h];
    }
    pctx[wave][h] = (c0 + c1) + (c2 + c3);
  }
  __syncthreads();
  if (tid < HID) {
    float s = pctx[0][tid];
#pragma unroll
    for (int w = 1; w < 8; ++w) s += pctx[w][tid];
    ctx[tid] = s;
  }
  __syncthreads();

  if (tid < NC) {
    const float* wr = fc_w + (size_t)tid * HID;
    float s0 = fc_b[tid], s1 = 0.f, s2 = 0.f, s3 = 0.f;
#pragma unroll
    for (int h = 0; h < HID; h += 4) {
      s0 += ctx[h] * wr[h];
      s1 += ctx[h + 1] * wr[h + 1];
      s2 += ctx[h + 2] * wr[h + 2];
      s3 += ctx[h + 3] * wr[h + 3];
    }
    dout[b * NC + tid] = (s0 + s1) + (s2 + s3);  // logits (B,250)
  }
}

// ---------------- launcher ----------------

extern "C" void kernel_launch(void* const* d_in, const int* in_sizes, int n_in,
                              void* d_out, int out_size, void* d_ws, size_t ws_size,
                              hipStream_t stream) {
  const float* x = (const float*)d_in[0];
  const float* wih_rh = (const float*)d_in[1];
  const float* whh_rh = (const float*)d_in[2];
  const float* bih_rh = (const float*)d_in[3];
  const float* bhh_rh = (const float*)d_in[4];
  const float* wih_ra = (const float*)d_in[5];
  const float* whh_ra = (const float*)d_in[6];
  const float* bih_ra = (const float*)d_in[7];
  const float* bhh_ra = (const float*)d_in[8];
  const float* wih_lh = (const float*)d_in[9];
  const float* whh_lh = (const float*)d_in[10];
  const float* bih_lh = (const float*)d_in[11];
  const float* bhh_lh = (const float*)d_in[12];
  const float* wih_la = (const float*)d_in[13];
  const float* whh_la = (const float*)d_in[14];
  const float* bih_la = (const float*)d_in[15];
  const float* bhh_la = (const float*)d_in[16];
  const float* att_w = (const float*)d_in[17];
  const float* fc_w = (const float*)d_in[18];
  const float* fc_b = (const float*)d_in[19];

  const size_t SZ_COMB = (size_t)BATCH * TLEN * HID * 4;     // 50,331,648
  const size_t SZ_FARM = (size_t)4 * TLEN * 32 * 8 * 2;      // 2,097,152
  const size_t SZ_F64  = (size_t)8 * TLEN * 16 * 64 * 2;     // 8,388,608
  const size_t SZ_F48  = (size_t)8 * TLEN * 16 * 48 * 2;     // 6,291,456
  const size_t SZ_PRE  = (size_t)8 * TLEN * 4096 * 2;        // 33,554,432
  const size_t NEED_FULL = SZ_COMB + 2 * SZ_FARM + 2 * SZ_F64 + 2 * SZ_PRE +
                           2 * 32768 + 2 * 32768 + 2 * 16384; // ~138.6 MB
  bool hoist = ws_size >= NEED_FULL;

  char* p = (char*)d_ws;
  float* combined = (float*)p;            p += SZ_COMB;
  unsigned short* fAR = (unsigned short*)p; p += SZ_FARM;
  unsigned short* fAL = (unsigned short*)p; p += SZ_FARM;
  unsigned short *fHR, *fHL, *preR = nullptr, *preL = nullptr;
  unsigned short *btA_r, *btA_l, *btH_r = nullptr, *btH_l = nullptr, *btArm_r, *btArm_l;
  if (hoist) {
    fHR = (unsigned short*)p; p += SZ_F64;
    fHL = (unsigned short*)p; p += SZ_F64;
    preR = (unsigned short*)p; p += SZ_PRE;
    preL = (unsigned short*)p; p += SZ_PRE;
    btA_r = (unsigned short*)p; p += 32768;
    btA_l = (unsigned short*)p; p += 32768;
    btH_r = (unsigned short*)p; p += 32768;
    btH_l = (unsigned short*)p; p += 32768;
  } else {
    fHR = (unsigned short*)p; p += SZ_F48;
    fHL = (unsigned short*)p; p += SZ_F48;
    btA_r = (unsigned short*)p; p += 65536;
    btA_l = (unsigned short*)p; p += 65536;
    btH_r = btA_r; btH_l = btA_l;  // unused in fb
  }
  btArm_r = (unsigned short*)p; p += 16384;
  btArm_l = (unsigned short*)p;

  prep_kernel<<<dim3((BATCH * TLEN + 255) / 256), 256, 0, stream>>>(
      x, fHR, fHL, fAR, fAL, hoist ? 64 : 48);
  pack_kernel<<<dim3(6), 256, 0, stream>>>(
      hoist ? 1 : 0,
      wih_rh, whh_rh, wih_ra, whh_ra, wih_lh, whh_lh, wih_la, whh_la,
      btA_r, btA_l, btH_r, btH_l, btArm_r, btArm_l);
  if (hoist) {
    pregemm_kernel<<<dim3(256), 256, 0, stream>>>(
        fHR, fHL, btA_r, btA_l, bih_rh, bhh_rh, bih_lh, bhh_lh, preR, preL);
    lstm_hoist<<<dim3(24), 256, 0, stream>>>(
        fAR, fAL, btH_r, btH_l, btArm_r, btArm_l, preR, preL,
        bih_ra, bhh_ra, bih_la, bhh_la, combined);
  } else {
    lstm_fb<<<dim3(24), 256, 0, stream>>>(
        fHR, fHL, fAR, fAL, btA_r, btA_l, btArm_r, btArm_l,
        bih_rh, bhh_rh, bih_ra, bhh_ra, bih_lh, bhh_lh, bih_la, bhh_la, combined);
  }
  attn_kernel<<<dim3(BATCH), 512, 0, stream>>>(combined, att_w, fc_w, fc_b, (float*)d_out);
}